// Round 1
// baseline (2277.991 us; speedup 1.0000x reference)
//
#include <hip/hip_runtime.h>
#include <hip/hip_bf16.h>
#include <stdint.h>

#define B 8
#define N 4096
#define C 1024
#define H 16
#define D 64
// SCALE = D^-0.5 = 0.125

static __device__ __forceinline__ float bf_lo(uint32_t u) {
    union { uint32_t i; float f; } c; c.i = u << 16; return c.f;
}
static __device__ __forceinline__ float bf_hi(uint32_t u) {
    union { uint32_t i; float f; } c; c.i = u & 0xffff0000u; return c.f;
}

// Kernel A: k[b,h,d] = emb[b,:] . Wk[hD+d,:]  ;  v likewise with Wv.
// One wave per output row; rows = B * 2C = 16384 waves.
__global__ void kv_kernel(const float* __restrict__ emb,
                          const float* __restrict__ Wk,
                          const float* __restrict__ Wv,
                          float* __restrict__ kbuf,
                          float* __restrict__ vbuf) {
    int wave = (blockIdx.x * blockDim.x + threadIdx.x) >> 6;
    int lane = threadIdx.x & 63;
    int b = wave / (2 * C);
    int r = wave % (2 * C);
    const float* Wrow = (r < C) ? (Wk + (size_t)r * C) : (Wv + (size_t)(r - C) * C);
    const float* e = emb + (size_t)b * C;
    float acc = 0.f;
#pragma unroll
    for (int j = 0; j < 4; ++j) {
        int c = (lane + 64 * j) * 4;
        float4 w4 = *(const float4*)(Wrow + c);
        float4 e4 = *(const float4*)(e + c);
        acc += w4.x * e4.x + w4.y * e4.y + w4.z * e4.z + w4.w * e4.w;
    }
#pragma unroll
    for (int off = 32; off; off >>= 1) acc += __shfl_xor(acc, off, 64);
    if (lane == 0) {
        if (r < C) kbuf[b * C + r] = acc;
        else       vbuf[b * C + (r - C)] = acc;
    }
}

// Kernel B: fold weights.
//   which==0: w[b,h,c]  = sum_d Wq[(hD+d)*C + c] * k[b,h,d]   (bf16 out)
//   which==1: U[b,h,c'] = sum_d Wp[c'*C + hD + d] * v[b,h,d]  (bf16 out)
// grid = B*H*2 blocks x 256 threads.
__global__ void wu_kernel(const float* __restrict__ Wq,
                          const float* __restrict__ Wp,
                          const float* __restrict__ kbuf,
                          const float* __restrict__ vbuf,
                          __hip_bfloat16* __restrict__ wbuf,
                          __hip_bfloat16* __restrict__ ubuf) {
    int id = blockIdx.x;
    int which = id & 1; id >>= 1;
    int h = id % H;
    int b = id / H;
    int t = threadIdx.x;
    if (which == 0) {
        const float* kk = kbuf + (size_t)(b * H + h) * D;
        int c = t * 4;
        float4 acc = {0.f, 0.f, 0.f, 0.f};
        for (int d = 0; d < D; ++d) {
            float kvs = kk[d];
            float4 w4 = *(const float4*)(Wq + (size_t)(h * D + d) * C + c);
            acc.x += kvs * w4.x; acc.y += kvs * w4.y;
            acc.z += kvs * w4.z; acc.w += kvs * w4.w;
        }
        __hip_bfloat16* o = wbuf + (size_t)(b * H + h) * C + c;
        o[0] = __float2bfloat16(acc.x); o[1] = __float2bfloat16(acc.y);
        o[2] = __float2bfloat16(acc.z); o[3] = __float2bfloat16(acc.w);
    } else {
        const float* vv = vbuf + (size_t)(b * H + h) * D;
        float4 v4[D / 4];
#pragma unroll
        for (int d4 = 0; d4 < D / 4; ++d4) v4[d4] = *(const float4*)(vv + d4 * 4);
#pragma unroll
        for (int cc = 0; cc < 4; ++cc) {
            int cp = t * 4 + cc;
            const float* wp = Wp + (size_t)cp * C + h * D;
            float acc = 0.f;
#pragma unroll
            for (int d4 = 0; d4 < D / 4; ++d4) {
                float4 w4 = *(const float4*)(wp + d4 * 4);
                acc += w4.x * v4[d4].x + w4.y * v4[d4].y
                     + w4.z * v4[d4].z + w4.w * v4[d4].w;
            }
            ubuf[(size_t)(b * H + h) * C + cp] = __float2bfloat16(acc);
        }
    }
}

// Kernel C: fused main pass. One wave per row.
// grid = (64, B), block = 256 (4 waves). Each block: 64 rows of batch b.
// LDS: w[b] and U[b] in bf16 (32KB + 32KB = 64KB) -> 2 blocks/CU.
__global__ void main_kernel(const float* __restrict__ fea,
                            const __hip_bfloat16* __restrict__ wbuf,
                            const __hip_bfloat16* __restrict__ ubuf,
                            const float* __restrict__ bp,
                            float* __restrict__ out) {
    __shared__ uint32_t w_s[H * C / 2];  // bf16x2 packed
    __shared__ uint32_t u_s[H * C / 2];
    const int b = blockIdx.y;
    const int tile = blockIdx.x;
    const int tid = threadIdx.x;

    // stage w[b], U[b] into LDS (uint4 = 8 bf16 per load)
    {
        const uint4* wsrc = (const uint4*)(wbuf + (size_t)b * H * C);
        const uint4* usrc = (const uint4*)(ubuf + (size_t)b * H * C);
        uint4* wdst = (uint4*)w_s;
        uint4* udst = (uint4*)u_s;
        for (int i = tid; i < H * C / 8; i += 256) {
            wdst[i] = wsrc[i];
            udst[i] = usrc[i];
        }
    }
    __syncthreads();

    const int lane = tid & 63;
    const int wv = tid >> 6;

    float4 bp4[4];
#pragma unroll
    for (int j = 0; j < 4; ++j) bp4[j] = *(const float4*)(bp + 4 * lane + 256 * j);

    for (int i = 0; i < 16; ++i) {
        const int n = tile * 64 + wv * 16 + i;
        const float* frow = fea + ((size_t)b * N + n) * C;
        float4 f[4];
#pragma unroll
        for (int j = 0; j < 4; ++j) f[j] = *(const float4*)(frow + 4 * lane + 256 * j);

        // s[h] = fea_row . w[b,h,:]
        float s[H];
#pragma unroll
        for (int h = 0; h < H; ++h) s[h] = 0.f;
#pragma unroll
        for (int h = 0; h < H; ++h) {
            const uint32_t* wrow = w_s + h * (C / 2);
#pragma unroll
            for (int j = 0; j < 4; ++j) {
                int di = 2 * lane + 128 * j;
                uint32_t p0 = wrow[di];
                uint32_t p1 = wrow[di + 1];
                s[h] += f[j].x * bf_lo(p0) + f[j].y * bf_hi(p0)
                      + f[j].z * bf_lo(p1) + f[j].w * bf_hi(p1);
            }
        }
        // butterfly reduce across 64 lanes (all lanes end with full sums)
#pragma unroll
        for (int off = 32; off; off >>= 1) {
#pragma unroll
            for (int h = 0; h < H; ++h) s[h] += __shfl_xor(s[h], off, 64);
        }
        float attn[H];
#pragma unroll
        for (int h = 0; h < H; ++h) attn[h] = 1.f / (1.f + __expf(-0.125f * s[h]));

        float* orow = out + ((size_t)b * N + n) * C;
#pragma unroll
        for (int j = 0; j < 4; ++j) {
            float4 acc = f[j];
            acc.x += bp4[j].x; acc.y += bp4[j].y;
            acc.z += bp4[j].z; acc.w += bp4[j].w;
#pragma unroll
            for (int h = 0; h < H; ++h) {
                const uint32_t* urow = u_s + h * (C / 2);
                int di = 2 * lane + 128 * j;
                uint32_t p0 = urow[di];
                uint32_t p1 = urow[di + 1];
                acc.x += attn[h] * bf_lo(p0); acc.y += attn[h] * bf_hi(p0);
                acc.z += attn[h] * bf_lo(p1); acc.w += attn[h] * bf_hi(p1);
            }
            *(float4*)(orow + 4 * lane + 256 * j) = acc;
        }
    }
}

extern "C" void kernel_launch(void* const* d_in, const int* in_sizes, int n_in,
                              void* d_out, int out_size, void* d_ws, size_t ws_size,
                              hipStream_t stream) {
    const float* fea = (const float*)d_in[0];
    const float* emb = (const float*)d_in[1];
    const float* Wq  = (const float*)d_in[2];
    const float* Wk  = (const float*)d_in[3];
    const float* Wv  = (const float*)d_in[4];
    const float* Wp  = (const float*)d_in[5];
    const float* bp  = (const float*)d_in[6];
    float* out = (float*)d_out;

    char* ws = (char*)d_ws;
    float* kbuf = (float*)ws;                                  // B*H*D f32 = 32KB
    float* vbuf = (float*)(ws + 32 * 1024);                    // 32KB
    __hip_bfloat16* wbuf = (__hip_bfloat16*)(ws + 64 * 1024);  // B*H*C bf16 = 256KB
    __hip_bfloat16* ubuf = (__hip_bfloat16*)(ws + 320 * 1024); // 256KB

    // A: 16384 waves -> 4096 blocks of 256
    hipLaunchKernelGGL(kv_kernel, dim3(B * 2 * C / 4), dim3(256), 0, stream,
                       emb, Wk, Wv, kbuf, vbuf);
    // B: fold weights
    hipLaunchKernelGGL(wu_kernel, dim3(B * H * 2), dim3(256), 0, stream,
                       Wq, Wp, kbuf, vbuf, wbuf, ubuf);
    // C: fused main pass
    hipLaunchKernelGGL(main_kernel, dim3(N / 64, B), dim3(256), 0, stream,
                       fea, wbuf, ubuf, bp, out);
}

// Round 3
// 1680.662 us; speedup vs baseline: 1.3554x; 1.3554x over previous
//
#include <hip/hip_runtime.h>
#include <hip/hip_bf16.h>
#include <stdint.h>

#define B 8
#define N 4096
#define C 1024
#define H 16
#define D 64
// SCALE = D^-0.5 = 0.125

typedef float vfloat4 __attribute__((ext_vector_type(4)));

static __device__ __forceinline__ float bf_lo(uint32_t u) {
    union { uint32_t i; float f; } c; c.i = u << 16; return c.f;
}
static __device__ __forceinline__ float bf_hi(uint32_t u) {
    union { uint32_t i; float f; } c; c.i = u & 0xffff0000u; return c.f;
}

// Kernel A: one wave per W row r (0..2C); computes k[b,*,r%C] (r<C) or v (r>=C)
// for ALL 8 batches -> W read exactly once. emb (32 KB) stays L1/L2-hot.
__global__ __launch_bounds__(256, 2)
void kv_kernel(const float* __restrict__ emb,
               const float* __restrict__ Wk,
               const float* __restrict__ Wv,
               float* __restrict__ kbuf,
               float* __restrict__ vbuf) {
    int wave = (blockIdx.x * blockDim.x + threadIdx.x) >> 6;  // 0..2047
    int lane = threadIdx.x & 63;
    int r = wave;
    const float* Wrow = (r < C) ? (Wk + (size_t)r * C) : (Wv + (size_t)(r - C) * C);
    float4 w4[4];
#pragma unroll
    for (int j = 0; j < 4; ++j) w4[j] = *(const float4*)(Wrow + (lane + 64 * j) * 4);
    float acc[B];
#pragma unroll
    for (int b = 0; b < B; ++b) {
        const float* e = emb + (size_t)b * C;
        float a = 0.f;
#pragma unroll
        for (int j = 0; j < 4; ++j) {
            float4 e4 = *(const float4*)(e + (lane + 64 * j) * 4);
            a += w4[j].x * e4.x + w4[j].y * e4.y + w4[j].z * e4.z + w4[j].w * e4.w;
        }
        acc[b] = a;
    }
#pragma unroll
    for (int off = 32; off; off >>= 1)
#pragma unroll
        for (int b = 0; b < B; ++b) acc[b] += __shfl_xor(acc[b], off, 64);
    if (lane == 0) {
        float* dst = (r < C) ? (kbuf + r) : (vbuf + (r - C));
#pragma unroll
        for (int b = 0; b < B; ++b) dst[b * C] = acc[b];
    }
}

// Kernel B: fold weights. block = (b,h,which).
//   which==0: w[b,h,c]  = sum_d Wq[(hD+d)*C + c] * k[b,h,d]   (bf16 out)
//   which==1: U[b,h,c'] = sum_d Wp[c'*C + hD + d] * v[b,h,d]  (bf16 out)
__global__ __launch_bounds__(256, 2)
void wu_kernel(const float* __restrict__ Wq,
               const float* __restrict__ Wp,
               const float* __restrict__ kbuf,
               const float* __restrict__ vbuf,
               __hip_bfloat16* __restrict__ wbuf,
               __hip_bfloat16* __restrict__ ubuf) {
    int id = blockIdx.x;
    int which = id & 1; id >>= 1;
    int h = id % H;
    int b = id / H;
    int t = threadIdx.x;
    if (which == 0) {
        const float* kk = kbuf + (size_t)(b * H + h) * D;
        int c = t * 4;
        float4 acc = {0.f, 0.f, 0.f, 0.f};
#pragma unroll 8
        for (int d = 0; d < D; ++d) {
            float kvs = kk[d];
            float4 w4 = *(const float4*)(Wq + (size_t)(h * D + d) * C + c);
            acc.x += kvs * w4.x; acc.y += kvs * w4.y;
            acc.z += kvs * w4.z; acc.w += kvs * w4.w;
        }
        __hip_bfloat16* o = wbuf + (size_t)(b * H + h) * C + c;
        o[0] = __float2bfloat16(acc.x); o[1] = __float2bfloat16(acc.y);
        o[2] = __float2bfloat16(acc.z); o[3] = __float2bfloat16(acc.w);
    } else {
        // 4 lanes per output row c'; lane-in-group q covers d = q*16 + 0..15.
        const int q = t & 3;
        const float* vv = vbuf + (size_t)(b * H + h) * D + q * 16;
        float4 v4[4];
#pragma unroll
        for (int m = 0; m < 4; ++m) v4[m] = *(const float4*)(vv + m * 4);
#pragma unroll
        for (int p = 0; p < 16; ++p) {
            int cp = p * 64 + (t >> 2);
            const float* wp = Wp + (size_t)cp * C + h * D + q * 16;
            float acc = 0.f;
#pragma unroll
            for (int m = 0; m < 4; ++m) {
                float4 w4 = *(const float4*)(wp + m * 4);
                acc += w4.x * v4[m].x + w4.y * v4[m].y
                     + w4.z * v4[m].z + w4.w * v4[m].w;
            }
            acc += __shfl_xor(acc, 1, 64);
            acc += __shfl_xor(acc, 2, 64);
            if (q == 0) ubuf[(size_t)(b * H + h) * C + cp] = __float2bfloat16(acc);
        }
    }
}

// Kernel C: fused main pass. One wave per row, 16 rows/wave.
// grid = (64, B), block = 256 (4 waves). LDS 64KB -> 2 blocks/CU (8 waves).
// __launch_bounds__(256,2): 2 waves/SIMD -> up to 256 VGPRs, NO spill.
__global__ __launch_bounds__(256, 2)
void main_kernel(const float* __restrict__ fea,
                 const __hip_bfloat16* __restrict__ wbuf,
                 const __hip_bfloat16* __restrict__ ubuf,
                 const float* __restrict__ bp,
                 float* __restrict__ out) {
    __shared__ uint32_t w_s[H * C / 2];  // bf16x2 packed
    __shared__ uint32_t u_s[H * C / 2];
    const int b = blockIdx.y;
    const int tile = blockIdx.x;
    const int tid = threadIdx.x;

    {
        const uint4* wsrc = (const uint4*)(wbuf + (size_t)b * H * C);
        const uint4* usrc = (const uint4*)(ubuf + (size_t)b * H * C);
        uint4* wdst = (uint4*)w_s;
        uint4* udst = (uint4*)u_s;
        for (int i = tid; i < H * C / 8; i += 256) {
            wdst[i] = wsrc[i];
            udst[i] = usrc[i];
        }
    }
    __syncthreads();

    const int lane = tid & 63;
    const int wv = tid >> 6;

    float4 bp4[4];
#pragma unroll
    for (int j = 0; j < 4; ++j) bp4[j] = *(const float4*)(bp + 4 * lane + 256 * j);

    const float* frow0 = fea + ((size_t)b * N + tile * 64 + wv * 16) * C;
    float4 f[4], fnext[4];
#pragma unroll
    for (int j = 0; j < 4; ++j) f[j] = *(const float4*)(frow0 + 4 * lane + 256 * j);

    for (int i = 0; i < 16; ++i) {
        // prefetch next row while this row computes
        if (i < 15) {
            const float* fr = frow0 + (size_t)(i + 1) * C;
#pragma unroll
            for (int j = 0; j < 4; ++j) fnext[j] = *(const float4*)(fr + 4 * lane + 256 * j);
        }

        // s[h] = fea_row . w[b,h,:]
        float s[H];
#pragma unroll
        for (int h = 0; h < H; ++h) s[h] = 0.f;
#pragma unroll
        for (int h = 0; h < H; ++h) {
            const uint32_t* wrow = w_s + h * (C / 2);
#pragma unroll
            for (int j = 0; j < 4; ++j) {
                int di = 2 * lane + 128 * j;
                uint32_t p0 = wrow[di];
                uint32_t p1 = wrow[di + 1];
                s[h] += f[j].x * bf_lo(p0) + f[j].y * bf_hi(p0)
                      + f[j].z * bf_lo(p1) + f[j].w * bf_hi(p1);
            }
        }
#pragma unroll
        for (int off = 32; off; off >>= 1) {
#pragma unroll
            for (int h = 0; h < H; ++h) s[h] += __shfl_xor(s[h], off, 64);
        }
        float attn[H];
#pragma unroll
        for (int h = 0; h < H; ++h) attn[h] = 1.f / (1.f + __expf(-0.125f * s[h]));

        float* orow = out + ((size_t)b * N + tile * 64 + wv * 16 + i) * C;
#pragma unroll
        for (int j = 0; j < 4; ++j) {
            float4 acc = f[j];
            acc.x += bp4[j].x; acc.y += bp4[j].y;
            acc.z += bp4[j].z; acc.w += bp4[j].w;
#pragma unroll
            for (int h = 0; h < H; ++h) {
                const uint32_t* urow = u_s + h * (C / 2);
                int di = 2 * lane + 128 * j;
                uint32_t p0 = urow[di];
                uint32_t p1 = urow[di + 1];
                acc.x += attn[h] * bf_lo(p0); acc.y += attn[h] * bf_hi(p0);
                acc.z += attn[h] * bf_lo(p1); acc.w += attn[h] * bf_hi(p1);
            }
            vfloat4 accv = {acc.x, acc.y, acc.z, acc.w};
            __builtin_nontemporal_store(accv, (vfloat4*)(orow + 4 * lane + 256 * j));
        }
#pragma unroll
        for (int j = 0; j < 4; ++j) f[j] = fnext[j];
    }
}

extern "C" void kernel_launch(void* const* d_in, const int* in_sizes, int n_in,
                              void* d_out, int out_size, void* d_ws, size_t ws_size,
                              hipStream_t stream) {
    const float* fea = (const float*)d_in[0];
    const float* emb = (const float*)d_in[1];
    const float* Wq  = (const float*)d_in[2];
    const float* Wk  = (const float*)d_in[3];
    const float* Wv  = (const float*)d_in[4];
    const float* Wp  = (const float*)d_in[5];
    const float* bp  = (const float*)d_in[6];
    float* out = (float*)d_out;

    char* ws = (char*)d_ws;
    float* kbuf = (float*)ws;                                  // B*H*D f32 = 32KB
    float* vbuf = (float*)(ws + 32 * 1024);                    // 32KB
    __hip_bfloat16* wbuf = (__hip_bfloat16*)(ws + 64 * 1024);  // B*H*C bf16 = 256KB
    __hip_bfloat16* ubuf = (__hip_bfloat16*)(ws + 320 * 1024); // 256KB

    // A: 2048 waves (one per W row, all batches) -> 512 blocks of 256
    hipLaunchKernelGGL(kv_kernel, dim3(2 * C / 4), dim3(256), 0, stream,
                       emb, Wk, Wv, kbuf, vbuf);
    // B: fold weights
    hipLaunchKernelGGL(wu_kernel, dim3(B * H * 2), dim3(256), 0, stream,
                       Wq, Wp, kbuf, vbuf, wbuf, ubuf);
    // C: fused main pass
    hipLaunchKernelGGL(main_kernel, dim3(N / 64, B), dim3(256), 0, stream,
                       fea, wbuf, ubuf, bp, out);
}

// Round 5
// 1380.820 us; speedup vs baseline: 1.6497x; 1.2171x over previous
//
#include <hip/hip_runtime.h>
#include <hip/hip_bf16.h>
#include <stdint.h>

#define B 8
#define N 4096
#define C 1024
#define H 16
#define D 64
// SCALE = D^-0.5 = 0.125

static __device__ __forceinline__ float bf_lo(uint32_t u) {
    union { uint32_t i; float f; } c; c.i = u << 16; return c.f;
}
static __device__ __forceinline__ float bf_hi(uint32_t u) {
    union { uint32_t i; float f; } c; c.i = u & 0xffff0000u; return c.f;
}

// Kernel A: one wave per W row r (0..2C); computes k[b,*,r] (r<C) or v (r>=C)
// for ALL 8 batches -> W read exactly once. emb (32 KB) stays L2-hot.
__global__ __launch_bounds__(256, 2)
void kv_kernel(const float* __restrict__ emb,
               const float* __restrict__ Wk,
               const float* __restrict__ Wv,
               float* __restrict__ kbuf,
               float* __restrict__ vbuf) {
    int wave = (blockIdx.x * blockDim.x + threadIdx.x) >> 6;  // 0..2047
    int lane = threadIdx.x & 63;
    int r = wave;
    const float* Wrow = (r < C) ? (Wk + (size_t)r * C) : (Wv + (size_t)(r - C) * C);
    float4 w4[4];
#pragma unroll
    for (int j = 0; j < 4; ++j) w4[j] = *(const float4*)(Wrow + (lane + 64 * j) * 4);
    float acc[B];
#pragma unroll
    for (int b = 0; b < B; ++b) {
        const float* e = emb + (size_t)b * C;
        float a = 0.f;
#pragma unroll
        for (int j = 0; j < 4; ++j) {
            float4 e4 = *(const float4*)(e + (lane + 64 * j) * 4);
            a += w4[j].x * e4.x + w4[j].y * e4.y + w4[j].z * e4.z + w4[j].w * e4.w;
        }
        acc[b] = a;
    }
#pragma unroll
    for (int off = 32; off; off >>= 1)
#pragma unroll
        for (int b = 0; b < B; ++b) acc[b] += __shfl_xor(acc[b], off, 64);
    if (lane == 0) {
        float* dst = (r < C) ? (kbuf + r) : (vbuf + (r - C));
#pragma unroll
        for (int b = 0; b < B; ++b) dst[b * C] = acc[b];
    }
}

// Kernel B: fold weights. block = (b,h,which).
//   which==0: w[b,h,c]  = sum_d Wq[(hD+d)*C + c] * k[b,h,d]   (bf16 out)
//   which==1: U[b,h,c'] = sum_d Wp[c'*C + hD + d] * v[b,h,d]  (bf16 out)
__global__ __launch_bounds__(256, 2)
void wu_kernel(const float* __restrict__ Wq,
               const float* __restrict__ Wp,
               const float* __restrict__ kbuf,
               const float* __restrict__ vbuf,
               __hip_bfloat16* __restrict__ wbuf,
               __hip_bfloat16* __restrict__ ubuf) {
    int id = blockIdx.x;
    int which = id & 1; id >>= 1;
    int h = id % H;
    int b = id / H;
    int t = threadIdx.x;
    if (which == 0) {
        const float* kk = kbuf + (size_t)(b * H + h) * D;
        int c = t * 4;
        float4 acc = {0.f, 0.f, 0.f, 0.f};
#pragma unroll 8
        for (int d = 0; d < D; ++d) {
            float kvs = kk[d];
            float4 w4 = *(const float4*)(Wq + (size_t)(h * D + d) * C + c);
            acc.x += kvs * w4.x; acc.y += kvs * w4.y;
            acc.z += kvs * w4.z; acc.w += kvs * w4.w;
        }
        __hip_bfloat16* o = wbuf + (size_t)(b * H + h) * C + c;
        o[0] = __float2bfloat16(acc.x); o[1] = __float2bfloat16(acc.y);
        o[2] = __float2bfloat16(acc.z); o[3] = __float2bfloat16(acc.w);
    } else {
        // 4 lanes per output row c'; lane-in-group q covers d = q*16 + 0..15.
        const int q = t & 3;
        const float* vv = vbuf + (size_t)(b * H + h) * D + q * 16;
        float4 v4[4];
#pragma unroll
        for (int m = 0; m < 4; ++m) v4[m] = *(const float4*)(vv + m * 4);
#pragma unroll
        for (int p = 0; p < 16; ++p) {
            int cp = p * 64 + (t >> 2);
            const float* wp = Wp + (size_t)cp * C + h * D + q * 16;
            float acc = 0.f;
#pragma unroll
            for (int m = 0; m < 4; ++m) {
                float4 w4 = *(const float4*)(wp + m * 4);
                acc += w4.x * v4[m].x + w4.y * v4[m].y
                     + w4.z * v4[m].z + w4.w * v4[m].w;
            }
            acc += __shfl_xor(acc, 1, 64);
            acc += __shfl_xor(acc, 2, 64);
            if (q == 0) ubuf[(size_t)(b * H + h) * C + cp] = __float2bfloat16(acc);
        }
    }
}

// Kernel C: fused main pass. One wave per row, 16 rows/wave.
// grid = (64, B), block = 256 (4 waves). LDS = exactly 64KB -> 2 blocks/CU.
// amdgpu_waves_per_eu(2,2): occupancy is LDS-bound at 2 waves/EU anyway, so
// pin the allocator to a 256-VGPR budget -> scheduler hoisting cannot spill.
// No register arrays that must survive phases: per-head scalar reduction with
// lane-h ownership, then v_readlane broadcasts for the epilogue.
__global__ __launch_bounds__(256)
__attribute__((amdgpu_waves_per_eu(2, 2)))
void main_kernel(const float* __restrict__ fea,
                 const __hip_bfloat16* __restrict__ wbuf,
                 const __hip_bfloat16* __restrict__ ubuf,
                 const float* __restrict__ bp,
                 float* __restrict__ out) {
    __shared__ uint32_t w_s[H * C / 2];  // bf16x2 packed, 32 KB
    __shared__ uint32_t u_s[H * C / 2];  // 32 KB
    const int b = blockIdx.y;
    const int tile = blockIdx.x;
    const int tid = threadIdx.x;

    {
        const uint4* wsrc = (const uint4*)(wbuf + (size_t)b * H * C);
        const uint4* usrc = (const uint4*)(ubuf + (size_t)b * H * C);
        uint4* wdst = (uint4*)w_s;
        uint4* udst = (uint4*)u_s;
#pragma unroll
        for (int i = 0; i < H * C / 8 / 256; ++i) {
            wdst[tid + i * 256] = wsrc[tid + i * 256];
            udst[tid + i * 256] = usrc[tid + i * 256];
        }
    }
    __syncthreads();

    const int lane = tid & 63;
    const int wv = tid >> 6;          // 0..3
    const int row0 = tile * 64 + wv * 16;

    float4 bp4[4];
#pragma unroll
    for (int j = 0; j < 4; ++j) bp4[j] = *(const float4*)(bp + 4 * lane + 256 * j);

#pragma unroll 1
    for (int i = 0; i < 16; ++i) {
        const float* frow = fea + ((size_t)b * N + row0 + i) * C;
        float4 f[4];
#pragma unroll
        for (int j = 0; j < 4; ++j) f[j] = *(const float4*)(frow + 4 * lane + 256 * j);

        // Per head: partial dot, butterfly, sigmoid; lane h keeps head h.
        float row_attn = 0.f;
#pragma unroll
        for (int h = 0; h < H; ++h) {
            const uint32_t* wrow = w_s + h * (C / 2) + 2 * lane;
            float s = 0.f;
#pragma unroll
            for (int j = 0; j < 4; ++j) {
                uint2 p = *(const uint2*)(wrow + 128 * j);
                s += f[j].x * bf_lo(p.x) + f[j].y * bf_hi(p.x)
                   + f[j].z * bf_lo(p.y) + f[j].w * bf_hi(p.y);
            }
#pragma unroll
            for (int off = 32; off; off >>= 1) s += __shfl_xor(s, off, 64);
            float sig = 1.f / (1.f + __expf(-0.125f * s));
            if (lane == h) row_attn = sig;
        }
        // Broadcast: a[h] comes from lane h (v_readlane -> SGPR-resident).
        float a[H];
#pragma unroll
        for (int h = 0; h < H; ++h) a[h] = __shfl(row_attn, h, 64);

        float* orow = out + ((size_t)b * N + row0 + i) * C;
#pragma unroll
        for (int j = 0; j < 4; ++j) {
            float4 acc = f[j];
            acc.x += bp4[j].x; acc.y += bp4[j].y;
            acc.z += bp4[j].z; acc.w += bp4[j].w;
            const uint32_t* urow = u_s + 2 * lane + 128 * j;
#pragma unroll
            for (int h = 0; h < H; ++h) {
                uint2 p = *(const uint2*)(urow + h * (C / 2));
                acc.x += a[h] * bf_lo(p.x); acc.y += a[h] * bf_hi(p.x);
                acc.z += a[h] * bf_lo(p.y); acc.w += a[h] * bf_hi(p.y);
            }
            *(float4*)(orow + 4 * lane + 256 * j) = acc;
        }
    }
}

extern "C" void kernel_launch(void* const* d_in, const int* in_sizes, int n_in,
                              void* d_out, int out_size, void* d_ws, size_t ws_size,
                              hipStream_t stream) {
    const float* fea = (const float*)d_in[0];
    const float* emb = (const float*)d_in[1];
    const float* Wq  = (const float*)d_in[2];
    const float* Wk  = (const float*)d_in[3];
    const float* Wv  = (const float*)d_in[4];
    const float* Wp  = (const float*)d_in[5];
    const float* bp  = (const float*)d_in[6];
    float* out = (float*)d_out;

    char* ws = (char*)d_ws;
    float* kbuf = (float*)ws;                                  // B*C f32 = 32KB
    float* vbuf = (float*)(ws + 32 * 1024);                    // 32KB
    __hip_bfloat16* wbuf = (__hip_bfloat16*)(ws + 64 * 1024);  // B*H*C bf16 = 256KB
    __hip_bfloat16* ubuf = (__hip_bfloat16*)(ws + 320 * 1024); // 256KB

    hipLaunchKernelGGL(kv_kernel, dim3(2 * C / 4), dim3(256), 0, stream,
                       emb, Wk, Wv, kbuf, vbuf);
    hipLaunchKernelGGL(wu_kernel, dim3(B * H * 2), dim3(256), 0, stream,
                       Wq, Wp, kbuf, vbuf, wbuf, ubuf);
    hipLaunchKernelGGL(main_kernel, dim3(N / 64, B), dim3(256), 0, stream,
                       fea, wbuf, ubuf, bp, out);
}